// Round 10
// baseline (277.302 us; speedup 1.0000x reference)
//
#include <hip/hip_runtime.h>

// QuantizedLinear: out[t][o] = sum_k x[t][k] * (w_q[o][k]-128)*scale[o] + bias[o]
// M=16, N=8192, K=8192. Memory-bound on w_q (256 MB int32, read once).
//
// R10: x in LDS (lgkmcnt path, decoupled from w's in-order vmcnt; relieves
// L1) + double-buffered chunks + RAW s_barrier with lgkmcnt(0)-only wait
// (HIP __syncthreads drains vmcnt(0), which killed R1's w-pipeline) + T14
// async-stage split (x global loads issued BEFORE the chunk's compute, so
// they are oldest in the vmcnt queue and never force w-prefetch drains;
// ds_write after compute). R9 failed because its x-loads were issued after
// w-prefetches: in-order vmcnt retirement collapsed the pipeline depth to 0.
// Safety of raw barrier: LDS produce/consume needs lgkmcnt(0) only; all
// global traffic here is read-only (w, x) so no vmcnt/global visibility is
// required at the barrier.

#define IN_F   8192
#define OUT_F  8192
#define NT     16
#define BLOCK  256
#define W_O    4
#define CH_PER_BLOCK 16        // 4 waves * W_O
#define K_CHUNK 512
#define NCHUNK (IN_F / K_CHUNK)  // 16

__global__ __launch_bounds__(BLOCK, 2)
void qlin_kernel(const float* __restrict__ x,     // [16][8192]
                 const int*   __restrict__ w_q,   // [8192][8192]
                 const float* __restrict__ scale, // [8192]
                 const float* __restrict__ bias,  // [8192]
                 float* __restrict__ out)         // [16][8192]
{
    __shared__ float xs[2][NT][K_CHUNK];          // 64 KB

    const int tid  = threadIdx.x;
    const int lane = tid & 63;
    const int wave = tid >> 6;
    const int o_base = blockIdx.x * CH_PER_BLOCK + wave * W_O;
    const int koff = lane * 4;

    const int* __restrict__ wr0 = w_q + (size_t)(o_base + 0) * IN_F;
    const int* __restrict__ wr1 = w_q + (size_t)(o_base + 1) * IN_F;
    const int* __restrict__ wr2 = w_q + (size_t)(o_base + 2) * IN_F;
    const int* __restrict__ wr3 = w_q + (size_t)(o_base + 3) * IN_F;

    float acc[NT][W_O];
#pragma unroll
    for (int t = 0; t < NT; ++t)
#pragma unroll
        for (int j = 0; j < W_O; ++j) acc[t][j] = 0.0f;

    float4 st[8];                                 // staged x, 32 VGPRs

    // stage regs <- global x chunk c (8 x float4 per thread, issued early)
#define STAGE_LOAD(c)                                                  \
    {                                                                  \
        _Pragma("unroll")                                              \
        for (int r = 0; r < 8; ++r) {                                  \
            const int flat = r * 1024 + tid * 4;                       \
            const int i = flat >> 9;                                   \
            const int k = flat & (K_CHUNK - 1);                        \
            st[r] = *reinterpret_cast<const float4*>(                  \
                &x[(size_t)i * IN_F + (c) * K_CHUNK + k]);             \
        }                                                              \
    }

#define STAGE_WRITE(buf)                                               \
    {                                                                  \
        _Pragma("unroll")                                              \
        for (int r = 0; r < 8; ++r) {                                  \
            const int flat = r * 1024 + tid * 4;                       \
            const int i = flat >> 9;                                   \
            const int k = flat & (K_CHUNK - 1);                        \
            *reinterpret_cast<float4*>(&xs[buf][i][k]) = st[r];        \
        }                                                              \
    }

    // LDS-only barrier: wait ds ops, skip the vmcnt(0) drain __syncthreads
    // would emit (keeps the w-stream in flight across chunk boundaries).
#define LDS_BARRIER()                                                  \
    asm volatile("s_waitcnt lgkmcnt(0)" ::: "memory");                 \
    __builtin_amdgcn_s_barrier();

    STAGE_LOAD(0)
    STAGE_WRITE(0)
    LDS_BARRIER()

#pragma unroll 1
    for (int c = 0; c < NCHUNK; ++c) {
        const int cur = c & 1;

        if (c + 1 < NCHUNK) STAGE_LOAD(c + 1)     // oldest vmcnt entries

        // ---- compute chunk c: 2 k-steps of 256, x via lgkmcnt ----
#pragma unroll
        for (int ks = 0; ks < K_CHUNK / 256; ++ks) {
            const int kg = c * K_CHUNK + ks * 256 + koff;
            int4 w0 = *reinterpret_cast<const int4*>(wr0 + kg);
            int4 w1 = *reinterpret_cast<const int4*>(wr1 + kg);
            int4 w2 = *reinterpret_cast<const int4*>(wr2 + kg);
            int4 w3 = *reinterpret_cast<const int4*>(wr3 + kg);

            float wf[W_O][4];
            wf[0][0] = (float)(w0.x - 128); wf[0][1] = (float)(w0.y - 128);
            wf[0][2] = (float)(w0.z - 128); wf[0][3] = (float)(w0.w - 128);
            wf[1][0] = (float)(w1.x - 128); wf[1][1] = (float)(w1.y - 128);
            wf[1][2] = (float)(w1.z - 128); wf[1][3] = (float)(w1.w - 128);
            wf[2][0] = (float)(w2.x - 128); wf[2][1] = (float)(w2.y - 128);
            wf[2][2] = (float)(w2.z - 128); wf[2][3] = (float)(w2.w - 128);
            wf[3][0] = (float)(w3.x - 128); wf[3][1] = (float)(w3.y - 128);
            wf[3][2] = (float)(w3.z - 128); wf[3][3] = (float)(w3.w - 128);

#pragma unroll
            for (int t = 0; t < NT; ++t) {
                const float4 xv = *reinterpret_cast<const float4*>(
                    &xs[cur][t][ks * 256 + koff]);
#pragma unroll
                for (int j = 0; j < W_O; ++j) {
                    acc[t][j] += wf[j][0] * xv.x;
                    acc[t][j] += wf[j][1] * xv.y;
                    acc[t][j] += wf[j][2] * xv.z;
                    acc[t][j] += wf[j][3] * xv.w;
                }
            }
        }

        if (c + 1 < NCHUNK) STAGE_WRITE(1 - cur)  // x long-retired by now
        LDS_BARRIER()
    }

#undef STAGE_LOAD
#undef STAGE_WRITE
#undef LDS_BARRIER

    // ---- cross-lane reduction: 64 (t,j) values, 6-step butterfly each ----
    float myval = 0.0f;
#pragma unroll
    for (int t = 0; t < NT; ++t) {
#pragma unroll
        for (int j = 0; j < W_O; ++j) {
            float v = acc[t][j];
#pragma unroll
            for (int off = 32; off > 0; off >>= 1)
                v += __shfl_xor(v, off, 64);
            if (lane == (t * W_O + j)) myval = v;
        }
    }

    const int t_o = lane >> 2;
    const int o   = o_base + (lane & 3);
    out[(size_t)t_o * OUT_F + o] = myval * scale[o] + bias[o];
}

extern "C" void kernel_launch(void* const* d_in, const int* in_sizes, int n_in,
                              void* d_out, int out_size, void* d_ws, size_t ws_size,
                              hipStream_t stream) {
    const float* x     = (const float*)d_in[0];
    const int*   w_q   = (const int*)d_in[1];
    const float* scale = (const float*)d_in[2];
    const float* bias  = (const float*)d_in[3];
    float*       out   = (float*)d_out;

    dim3 grid(OUT_F / CH_PER_BLOCK);   // 512 blocks -> 2 per CU
    dim3 block(BLOCK);
    qlin_kernel<<<grid, block, 0, stream>>>(x, w_q, scale, bias, out);
}